// Round 14
// baseline (821.118 us; speedup 1.0000x reference)
//
#include <hip/hip_runtime.h>

namespace {

constexpr int NBATCH = 2048;
constexpr int NT     = 200;

typedef _Float16 f16x8 __attribute__((ext_vector_type(8)));
typedef float    f32x16 __attribute__((ext_vector_type(16)));
typedef int      i32x2  __attribute__((ext_vector_type(2)));

struct Frag2 { f16x8 h, l; };

// Exact 2-way split of fp32 into f16 hi/lo (11-bit mantissa each, RTNE).
// r = v - h is exact in fp32 (Sterbenz); h + l represents v to ~2^-23 rel.
__device__ inline Frag2 split2_8(const float f[8]) {
  Frag2 r;
  #pragma unroll
  for (int e = 0; e < 8; ++e) {
    const float v = f[e];
    const _Float16 hH = (_Float16)v;         // RTNE
    const float r1 = v - (float)hH;          // exact
    r.h[e] = hH;
    r.l[e] = (_Float16)r1;                   // RTNE; drops ~2^-23 rel
  }
  return r;
}

// Cross-term group (lh, hl ~ 2^-11|D|) — accumulate separately from hh so
// rounding happens at ulp(2^-11|D|). Merge in fp32 VALU afterwards.
__device__ inline f32x16 mm_lo(f32x16 acc, const Frag2& a, const Frag2& b) {
  acc = __builtin_amdgcn_mfma_f32_32x32x16_f16(a.l, b.h, acc, 0, 0, 0);
  acc = __builtin_amdgcn_mfma_f32_32x32x16_f16(a.h, b.l, acc, 0, 0, 0);
  return acc;
}
__device__ inline f32x16 mm_hh(f32x16 acc, const Frag2& a, const Frag2& b) {
  return __builtin_amdgcn_mfma_f32_32x32x16_f16(a.h, b.h, acc, 0, 0, 0);
}

// v_permlane32_swap_b32: out0 = {a.lanes0-31, b.lanes0-31},
//                        out1 = {a.lanes32-63, b.lanes32-63}.
// Semantics hardware-verified in round 9 (bit-identical pass).
__device__ inline void half_swap(float a, float b, float& oa, float& ob) {
  i32x2 r = __builtin_amdgcn_permlane32_swap(
      __float_as_int(a), __float_as_int(b), false, false);
  oa = __int_as_float(r[0]);
  ob = __int_as_float(r[1]);
}

// C/D-layout regs -> B-operand Frag2 pair, all-VALU via permlane32_swap.
__device__ inline void cd_to_bfrag(const f32x16 cd, Frag2 out[2]) {
  #pragma unroll
  for (int h = 0; h < 2; ++h) {
    float f[8];
    const int base = 8 * h;
    #pragma unroll
    for (int e = 0; e < 4; ++e)
      half_swap(cd[base + e], cd[base + 4 + e], f[e], f[4 + e]);
    out[h] = split2_8(f);
  }
}

// Precompute QG[b][t][j] = (Q_b * goal_t)[j] for t = 0..200.
// Same ascending-m FMA chain as the in-loop version -> bit-identical.
__global__ __launch_bounds__(64) void qg_kernel(
    const float* __restrict__ gQ, const float* __restrict__ gG,
    float* __restrict__ QG)
{
    __shared__ float sQ[1024];
    const int lane = threadIdx.x;
    const int b    = blockIdx.x;
    const float* __restrict__ Qb = gQ + (size_t)b * 1024;
    const float* __restrict__ Gb = gG + (size_t)b * (201 * 32);
    float* __restrict__ QGb = QG + (size_t)b * (201 * 32);
    #pragma unroll
    for (int m = 0; m < 4; ++m)
        reinterpret_cast<float4*>(sQ)[lane + 64 * m] =
            reinterpret_cast<const float4*>(Qb)[lane + 64 * m];
    const int jj = lane & 31, th = lane >> 5;
    for (int t = th; t < 201; t += 2) {
        const float* __restrict__ g = Gb + t * 32;
        float acc = 0.f;
        #pragma unroll
        for (int m = 0; m < 32; ++m) acc += sQ[m * 32 + jj] * g[m];
        QGb[t * 32 + jj] = acc;
    }
}

// One wave = one batch element, 200-step backward Riccati recursion.
// R4/R7-proven CONSISTENT algebra (every product consumes the same literal V~):
//   P   = V~^T A  (MFMA, VF-as-A-op) ; BtV = B^T V~ (MFMA) -> LDS
//   M2  = BtV * A (MFMA on the LITERAL LDS BtV; B-op = AtF reused)
//   Vuu = R + BtV*B (slim fp32 VALU loop) ; Kg = Vuu^-1 M2 (shfl GJ)
//   ABK = A - B*Kg (fp32 cancel FIRST)
//   V'  = P^T * ABK + Q (MFMA, PF-as-A-op = literal P^T = A^T V~)
//   v'  = A^T v - Kg^T (B^T v) + QG[step]
// MFMA 32x32x16 layouts (verified rounds 2-4; f16 same mapping as bf16):
//   A-frag: lane holds A'[l&31][16h + 8*(l>>5) + e]
//   B-frag: lane holds B'[16h + 8*(l>>5) + e][l&31]
//   C/D   : lane holds C[(r&3) + 8*(r>>2) + 4*(l>>5)][l&31]
template <bool USE_QG>
__global__ __launch_bounds__(64, 2) void lqr_kernel(
    const float* __restrict__ gA,   // [B,32,32]
    const float* __restrict__ gB,   // [B,32,8]
    const float* __restrict__ gQ,   // [B,32,32]
    const float* __restrict__ gR,   // [B,8,8]
    const float* __restrict__ gG,   // [B,201,32]
    const float* __restrict__ gQG,  // [B,201,32] precomputed Q*goal (or null)
    float* __restrict__ outK,       // [T,B,8,32]
    float* __restrict__ outk)       // [T,B,8]
{
    __shared__ __attribute__((aligned(16))) float smem[4104];
    float* const sA   = smem;          // [32][32] row-major
    float* const sQ   = smem + 1024;   // [32][32] (fallback Q*goal only)
    float* const sAt  = smem + 2048;   // [32][36] A^T, pad 36 (v' b128 rows)
    float* const sBp  = smem + 3200;   // [32][9]  B padded
    float* const sBtV = smem + 3488;   // [8][36]  B^T V ; aliased as Kg later
    float* const sM2  = smem + 3776;   // [8][36]  BtV*A
    float* const svv  = smem + 4064;   // [32] running v
    float* const sbtv = smem + 4096;   // [8]  B^T v

    const int lane = threadIdx.x;
    const int b    = blockIdx.x;
    const int ig   = lane >> 3;        // 0..7
    const int kg   = lane & 7;         // 0..7
    const int k0   = kg << 2;
    const int jj   = lane & 31;
    const int col  = lane & 31;        // MFMA col within tile
    const int up   = lane >> 5;        // 0/1: lane-half

    const float* __restrict__ Ab = gA + (size_t)b * 1024;
    const float* __restrict__ Bb = gB + (size_t)b * 256;
    const float* __restrict__ Qb = gQ + (size_t)b * 1024;
    const float* __restrict__ Gb = gG + (size_t)b * (201 * 32);
    const float* __restrict__ QGb = USE_QG ? gQG + (size_t)b * (201 * 32) : nullptr;

    // ---------------- one-time staging ----------------
    #pragma unroll
    for (int m = 0; m < 4; ++m)
        reinterpret_cast<float4*>(sA)[lane + 64 * m] =
            reinterpret_cast<const float4*>(Ab)[lane + 64 * m];
    if constexpr (!USE_QG) {
        #pragma unroll
        for (int m = 0; m < 4; ++m)
            reinterpret_cast<float4*>(sQ)[lane + 64 * m] =
                reinterpret_cast<const float4*>(Qb)[lane + 64 * m];
    }
    // A^T tile for the v' row-major b128 reads
    #pragma unroll
    for (int t = 0; t < 16; ++t) {
        const int mm = 2 * t + up;
        sAt[col * 36 + mm] = Ab[mm * 32 + col];
    }
    {
        float4 b4 = reinterpret_cast<const float4*>(Bb)[lane];
        const int fb = lane * 4;
        sBp[((fb + 0) >> 3) * 9 + ((fb + 0) & 7)] = b4.x;
        sBp[((fb + 1) >> 3) * 9 + ((fb + 1) & 7)] = b4.y;
        sBp[((fb + 2) >> 3) * 9 + ((fb + 2) & 7)] = b4.z;
        sBp[((fb + 3) >> 3) * 9 + ((fb + 3) & 7)] = b4.w;
    }
    const float rreg = gR[(size_t)b * 64 + lane];   // R[ig][kg]

    // AtF: A-frag of A^T AND B-frag of A (both read A[k][col]).
    Frag2 AtF[2];
    #pragma unroll
    for (int h = 0; h < 2; ++h) {
        float f[8];
        #pragma unroll
        for (int e = 0; e < 8; ++e) f[e] = Ab[(16 * h + 8 * up + e) * 32 + col];
        AtF[h] = split2_8(f);
    }
    // B^T zero-padded to 32x32 as A-frag
    Frag2 BtF[2];
    #pragma unroll
    for (int h = 0; h < 2; ++h) {
        float f[8];
        #pragma unroll
        for (int e = 0; e < 8; ++e)
            f[e] = (col < 8) ? Bb[(16 * h + 8 * up + e) * 8 + col] : 0.f;
        BtF[h] = split2_8(f);
    }
    // B as A-operand for B*Kg (32x8 in one K=16 tile: k=8up+e, up=1 half zero)
    Frag2 BFa;
    {
        float f[8];
        #pragma unroll
        for (int e = 0; e < 8; ++e) f[e] = up ? 0.f : Bb[col * 8 + e];
        BFa = split2_8(f);
    }
    // A and Q in C/D layout (register-resident addends)
    f32x16 afr, qfr;
    #pragma unroll
    for (int r = 0; r < 16; ++r) {
        const int row = (r & 3) + 8 * (r >> 2) + 4 * up;
        afr[r] = Ab[row * 32 + col];
        qfr[r] = Qb[row * 32 + col];
    }

    // v0 = Q * goals[:, T, :]
    if constexpr (USE_QG) {
        if (lane < 32) svv[jj] = QGb[200 * 32 + jj];
    } else {
        const float* __restrict__ gl = Gb + 200 * 32;
        float t = 0.f;
        #pragma unroll
        for (int m = 0; m < 32; ++m) t += sQ[m * 32 + jj] * gl[m];
        if (lane < 32) svv[jj] = t;
    }

    // Persistent zero accumulator seed: every MFMA chain starts from these
    // regs instead of 16 v_mov zero-inits per chain per step (9 chains =
    // ~144 movs/step saved). Bit-identical: chains still start from 0.0.
    f32x16 z16;
    #pragma unroll
    for (int r = 0; r < 16; ++r) z16[r] = 0.f;

    f32x16 vacc = qfr;   // V0 = Q, held in C/D layout across steps
    const float* __restrict__ qgp = USE_QG ? QGb + 199 * 32 : nullptr;

    for (int c = 0; c < NT; ++c) {
        const int step = NT - 1 - c;

        // t2 = (Q * goal_step)[jj] — one coalesced load (or fallback loop)
        float t2;
        if constexpr (USE_QG) {
            t2 = qgp[jj];
        } else {
            const float* __restrict__ grow = Gb + step * 32;
            t2 = 0.f;
            #pragma unroll
            for (int m = 0; m < 32; ++m) t2 += sQ[m * 32 + jj] * grow[m];
        }

        // ---- V (C/D regs) -> frag (B-frag layout), all-VALU permlane path
        Frag2 VF[2];
        cd_to_bfrag(vacc, VF);

        // ---- BtV = (B^T pad) V~ (1-acc small-first), then P = V~^T A
        __builtin_amdgcn_s_setprio(1);
        f32x16 bacc, pC, pB;
        bacc = mm_lo(z16, BtF[0], VF[0]);
        bacc = mm_lo(bacc, BtF[1], VF[1]);
        bacc = mm_hh(bacc, BtF[0], VF[0]);
        bacc = mm_hh(bacc, BtF[1], VF[1]);
        pC = mm_lo(z16, VF[0], AtF[0]);
        pC = mm_lo(pC, VF[1], AtF[1]);
        pB = mm_hh(z16, VF[0], AtF[0]);
        pB = mm_hh(pB, VF[1], AtF[1]);
        __builtin_amdgcn_s_setprio(0);

        // ---- btv[u] = sum_j B[j][u] * v[j] (VALU; overlaps MFMAs)
        {
            const int u = lane & 7, q8 = lane >> 3;
            const float4 v4 = *reinterpret_cast<const float4*>(&svv[4 * q8]);
            float p = 0.f;
            p += sBp[(4 * q8 + 0) * 9 + u] * v4.x;
            p += sBp[(4 * q8 + 1) * 9 + u] * v4.y;
            p += sBp[(4 * q8 + 2) * 9 + u] * v4.z;
            p += sBp[(4 * q8 + 3) * 9 + u] * v4.w;
            p += __shfl_xor(p, 8, 64);
            p += __shfl_xor(p, 16, 64);
            p += __shfl_xor(p, 32, 64);
            if (lane < 8) sbtv[u] = p;
        }

        // ---- BtV rows 0..7 -> LDS
        #pragma unroll
        for (int q = 0; q < 4; ++q)
            sBtV[(q + 4 * up) * 36 + col] = bacc[q];

        // ---- BtV as A-operand (transpose read of the LITERAL LDS BtV;
        //      rows >= 8 of the padded 32x32 are zero)
        Frag2 BtVaF[2];
        #pragma unroll
        for (int h = 0; h < 2; ++h) {
            float f[8];
            #pragma unroll
            for (int e = 0; e < 8; ++e)
                f[e] = (col < 8) ? sBtV[col * 36 + 16 * h + 8 * up + e] : 0.f;
            BtVaF[h] = split2_8(f);
        }

        // ---- M2 = BtV * A via MFMA (2-acc; B-op = AtF reused).
        __builtin_amdgcn_s_setprio(1);
        f32x16 mC, mB;
        mC = mm_lo(z16, BtVaF[0], AtF[0]);
        mC = mm_lo(mC, BtVaF[1], AtF[1]);
        mB = mm_hh(z16, BtVaF[0], AtF[0]);
        mB = mm_hh(mB, BtVaF[1], AtF[1]);
        __builtin_amdgcn_s_setprio(0);

        // ---- Vuu = R + BtV*B (slim fp32 loop; overlaps the M2 MFMAs)
        float cur, cur8;
        {
            float vu = rreg;
            #pragma unroll
            for (int jb = 0; jb < 8; ++jb) {
                const float4 bt4 = *reinterpret_cast<const float4*>(&sBtV[ig * 36 + 4 * jb]);
                vu += bt4.x * sBp[(4 * jb + 0) * 9 + kg];
                vu += bt4.y * sBp[(4 * jb + 1) * 9 + kg];
                vu += bt4.z * sBp[(4 * jb + 2) * 9 + kg];
                vu += bt4.w * sBp[(4 * jb + 3) * 9 + kg];
            }
            cur  = vu;
            cur8 = (ig == kg) ? 1.f : 0.f;
        }

        // ---- M2 merge -> LDS (rows q+4up; mC/mB die here, before GJ)
        #pragma unroll
        for (int q = 0; q < 4; ++q)
            sM2[(q + 4 * up) * 36 + col] = mC[q] + mB[q];

        // ---- Gauss-Jordan inverse of Vuu in registers via shfl.
        // Lane (ig,kg) holds [Vuu|I][ig][kg]. PD with diag>=1 -> no pivoting.
        #pragma unroll
        for (int p = 0; p < 8; ++p) {
            const float piv = __shfl(cur, p * 8 + p, 64);
            const float rp  = 1.0f / piv;
            const float pc  = __shfl(cur,  p * 8 + kg, 64);
            const float pc8 = __shfl(cur8, p * 8 + kg, 64);
            const float mrp = __shfl(cur,  ig * 8 + p, 64);
            const float fgj = mrp * rp;
            const bool  isp = (ig == p);
            cur  = isp ? pc  * rp : cur  - fgj * pc;
            cur8 = isp ? pc8 * rp : cur8 - fgj * pc8;
        }

        // ---- merge P, build P frag (B-frag layout; as A-op it is P^T = A^T V~)
        f32x16 pM;
        #pragma unroll
        for (int r = 0; r < 16; ++r) pM[r] = pC[r] + pB[r];
        Frag2 PF[2];
        cd_to_bfrag(pM, PF);

        // ---- P3: Kg = Vuu_inv * M2 ; kf = Vuu_inv * btv ; write outputs
        float* const sKg = sBtV;   // BtV dead after Vuu + BtVaF build
        {
            float ka0 = 0, ka1 = 0, ka2 = 0, ka3 = 0, kfv = 0;
            #pragma unroll
            for (int u2 = 0; u2 < 8; ++u2) {
                const float  w  = __shfl(cur8, ig * 8 + u2, 64);   // inv[ig][u2]
                const float4 m4 = *reinterpret_cast<const float4*>(&sM2[u2 * 36 + k0]);
                const float  bt = sbtv[u2];
                ka0 += w * m4.x; ka1 += w * m4.y; ka2 += w * m4.z; ka3 += w * m4.w;
                kfv += w * bt;
            }
            *reinterpret_cast<float4*>(&sKg[ig * 36 + k0]) = make_float4(ka0, ka1, ka2, ka3);
            const size_t ob = (size_t)step * NBATCH + b;
            *reinterpret_cast<float4*>(&outK[ob * 256 + ig * 32 + k0]) =
                make_float4(ka0, ka1, ka2, ka3);
            if (kg == 0) outk[ob * 8 + ig] = kfv;
        }

        // ---- Kg as B-operand (one K=16 tile: rows 8up+e; up=1 half zero)
        Frag2 KgF;
        {
            float fk[8];
            #pragma unroll
            for (int e = 0; e < 8; ++e)
                fk[e] = up ? 0.f : sKg[e * 36 + col];
            KgF = split2_8(fk);
        }

        // ---- BKg = B * Kg (emulated, 2-acc); ABK = A - BKg in fp32 (C/D regs)
        __builtin_amdgcn_s_setprio(1);
        f32x16 bkC, bkB;
        bkC = mm_lo(z16, BFa, KgF);
        bkB = mm_hh(z16, BFa, KgF);
        __builtin_amdgcn_s_setprio(0);
        f32x16 abk;
        #pragma unroll
        for (int r = 0; r < 16; ++r) abk[r] = afr[r] - (bkC[r] + bkB[r]);

        // ---- KF: ABK as B-frag (from registers; no LDS roundtrip)
        Frag2 KF[2];
        cd_to_bfrag(abk, KF);

        // ---- V' = P^T * ABK + Q (PF as A-op; 2-acc; Q added last in fp32)
        __builtin_amdgcn_s_setprio(1);
        f32x16 vC, vB;
        vC = mm_lo(z16, PF[0], KF[0]);
        vC = mm_lo(vC, PF[1], KF[1]);
        vB = mm_hh(z16, PF[0], KF[0]);
        vB = mm_hh(vB, PF[1], KF[1]);
        __builtin_amdgcn_s_setprio(0);

        // ---- v' = A^T v - Kg^T btv + QG (VALU; overlaps V' MFMAs)
        {
            float t1 = 0.f;
            #pragma unroll
            for (int kb = 0; kb < 8; ++kb) {
                const float4 a4 = *reinterpret_cast<const float4*>(&sAt[jj * 36 + 4 * kb]);
                const float4 v4 = *reinterpret_cast<const float4*>(&svv[4 * kb]);
                t1 += a4.x * v4.x; t1 += a4.y * v4.y;
                t1 += a4.z * v4.z; t1 += a4.w * v4.w;
            }
            float tk = 0.f;
            #pragma unroll
            for (int u = 0; u < 8; ++u) tk += sKg[u * 36 + jj] * sbtv[u];
            if (lane < 32) svv[jj] = (t1 - tk) + t2;
        }

        // ---- final merge: small terms first, Q last in fp32
        #pragma unroll
        for (int r = 0; r < 16; ++r) vacc[r] = (vC[r] + vB[r]) + qfr[r];

        if constexpr (USE_QG) qgp -= 32;
    }
}

}  // namespace

extern "C" void kernel_launch(void* const* d_in, const int* in_sizes, int n_in,
                              void* d_out, int out_size, void* d_ws, size_t ws_size,
                              hipStream_t stream) {
    const float* A = (const float*)d_in[0];
    const float* B = (const float*)d_in[1];
    const float* Q = (const float*)d_in[2];
    const float* R = (const float*)d_in[3];
    const float* G = (const float*)d_in[4];
    float* outK = (float*)d_out;
    float* outk = outK + (size_t)NT * NBATCH * 8 * 32;

    const size_t need = (size_t)NBATCH * 201 * 32 * sizeof(float);
    if (ws_size >= need) {
        float* QG = (float*)d_ws;
        qg_kernel<<<dim3(NBATCH), dim3(64), 0, stream>>>(Q, G, QG);
        lqr_kernel<true><<<dim3(NBATCH), dim3(64), 0, stream>>>(
            A, B, Q, R, G, QG, outK, outk);
    } else {
        lqr_kernel<false><<<dim3(NBATCH), dim3(64), 0, stream>>>(
            A, B, Q, R, G, nullptr, outK, outk);
    }
}

// Round 15
// 789.986 us; speedup vs baseline: 1.0394x; 1.0394x over previous
//
#include <hip/hip_runtime.h>

namespace {

constexpr int NBATCH = 2048;
constexpr int NT     = 200;

typedef _Float16 f16x8 __attribute__((ext_vector_type(8)));
typedef float    f32x16 __attribute__((ext_vector_type(16)));
typedef int      i32x2  __attribute__((ext_vector_type(2)));

struct Frag2 { f16x8 h, l; };

// Exact 2-way split of fp32 into f16 hi/lo (11-bit mantissa each, RTNE).
// r = v - h is exact in fp32 (Sterbenz); h + l represents v to ~2^-23 rel.
__device__ inline Frag2 split2_8(const float f[8]) {
  Frag2 r;
  #pragma unroll
  for (int e = 0; e < 8; ++e) {
    const float v = f[e];
    const _Float16 hH = (_Float16)v;         // RTNE
    const float r1 = v - (float)hH;          // exact
    r.h[e] = hH;
    r.l[e] = (_Float16)r1;                   // RTNE; drops ~2^-23 rel
  }
  return r;
}

// Cross-term group (lh, hl ~ 2^-11|D|) — accumulate separately from hh so
// rounding happens at ulp(2^-11|D|). Merge in fp32 VALU afterwards.
__device__ inline f32x16 mm_lo(f32x16 acc, const Frag2& a, const Frag2& b) {
  acc = __builtin_amdgcn_mfma_f32_32x32x16_f16(a.l, b.h, acc, 0, 0, 0);
  acc = __builtin_amdgcn_mfma_f32_32x32x16_f16(a.h, b.l, acc, 0, 0, 0);
  return acc;
}
__device__ inline f32x16 mm_hh(f32x16 acc, const Frag2& a, const Frag2& b) {
  return __builtin_amdgcn_mfma_f32_32x32x16_f16(a.h, b.h, acc, 0, 0, 0);
}

// v_permlane32_swap_b32: out0 = {a.lanes0-31, b.lanes0-31},
//                        out1 = {a.lanes32-63, b.lanes32-63}.
// Semantics hardware-verified in round 9 (bit-identical pass).
__device__ inline void half_swap(float a, float b, float& oa, float& ob) {
  i32x2 r = __builtin_amdgcn_permlane32_swap(
      __float_as_int(a), __float_as_int(b), false, false);
  oa = __int_as_float(r[0]);
  ob = __int_as_float(r[1]);
}

// C/D-layout regs -> B-operand Frag2 pair, all-VALU via permlane32_swap.
__device__ inline void cd_to_bfrag(const f32x16 cd, Frag2 out[2]) {
  #pragma unroll
  for (int h = 0; h < 2; ++h) {
    float f[8];
    const int base = 8 * h;
    #pragma unroll
    for (int e = 0; e < 4; ++e)
      half_swap(cd[base + e], cd[base + 4 + e], f[e], f[4 + e]);
    out[h] = split2_8(f);
  }
}

// Precompute QG[b][t][j] = (Q_b * goal_t)[j] for t = 0..200.
// Same ascending-m FMA chain as the in-loop version -> bit-identical.
__global__ __launch_bounds__(64) void qg_kernel(
    const float* __restrict__ gQ, const float* __restrict__ gG,
    float* __restrict__ QG)
{
    __shared__ float sQ[1024];
    const int lane = threadIdx.x;
    const int b    = blockIdx.x;
    const float* __restrict__ Qb = gQ + (size_t)b * 1024;
    const float* __restrict__ Gb = gG + (size_t)b * (201 * 32);
    float* __restrict__ QGb = QG + (size_t)b * (201 * 32);
    #pragma unroll
    for (int m = 0; m < 4; ++m)
        reinterpret_cast<float4*>(sQ)[lane + 64 * m] =
            reinterpret_cast<const float4*>(Qb)[lane + 64 * m];
    const int jj = lane & 31, th = lane >> 5;
    for (int t = th; t < 201; t += 2) {
        const float* __restrict__ g = Gb + t * 32;
        float acc = 0.f;
        #pragma unroll
        for (int m = 0; m < 32; ++m) acc += sQ[m * 32 + jj] * g[m];
        QGb[t * 32 + jj] = acc;
    }
}

// One wave = one batch element, 200-step backward Riccati recursion.
// R4/R7-proven CONSISTENT algebra (every product consumes the same literal V~):
//   P   = V~^T A  (MFMA, VF-as-A-op) ; BtV = B^T V~ (MFMA) -> LDS
//   M2  = BtV * A (MFMA on the LITERAL LDS BtV; B-op = AtF reused)
//   Vuu = R + BtV*B (slim fp32 VALU loop) ; Kg = Vuu^-1 M2 (shfl GJ)
//   ABK = A - B*Kg (fp32 cancel FIRST)
//   V'  = P^T * ABK + Q (MFMA, PF-as-A-op = literal P^T = A^T V~)
//   v'  = A^T v - Kg^T (B^T v) + QG[step]
// MFMA 32x32x16 layouts (verified rounds 2-4; f16 same mapping as bf16):
//   A-frag: lane holds A'[l&31][16h + 8*(l>>5) + e]
//   B-frag: lane holds B'[16h + 8*(l>>5) + e][l&31]
//   C/D   : lane holds C[(r&3) + 8*(r>>2) + 4*(l>>5)][l&31]
template <bool USE_QG>
__global__ __launch_bounds__(64, 2) void lqr_kernel(
    const float* __restrict__ gA,   // [B,32,32]
    const float* __restrict__ gB,   // [B,32,8]
    const float* __restrict__ gQ,   // [B,32,32]
    const float* __restrict__ gR,   // [B,8,8]
    const float* __restrict__ gG,   // [B,201,32]
    const float* __restrict__ gQG,  // [B,201,32] precomputed Q*goal (or null)
    float* __restrict__ outK,       // [T,B,8,32]
    float* __restrict__ outk)       // [T,B,8]
{
    __shared__ __attribute__((aligned(16))) float smem[4104];
    float* const sA   = smem;          // [32][32] row-major
    float* const sQ   = smem + 1024;   // [32][32] (fallback Q*goal only)
    float* const sAt  = smem + 2048;   // [32][36] A^T, pad 36 (v' b128 rows)
    float* const sBp  = smem + 3200;   // [32][9]  B padded
    float* const sBtV = smem + 3488;   // [8][36]  B^T V ; aliased as Kg later
    float* const sM2  = smem + 3776;   // [8][36]  BtV*A
    float* const svv  = smem + 4064;   // [32] running v
    float* const sbtv = smem + 4096;   // [8]  B^T v

    const int lane = threadIdx.x;
    const int b    = blockIdx.x;
    const int ig   = lane >> 3;        // 0..7
    const int kg   = lane & 7;         // 0..7
    const int k0   = kg << 2;
    const int jj   = lane & 31;
    const int col  = lane & 31;        // MFMA col within tile
    const int up   = lane >> 5;        // 0/1: lane-half

    const float* __restrict__ Ab = gA + (size_t)b * 1024;
    const float* __restrict__ Bb = gB + (size_t)b * 256;
    const float* __restrict__ Qb = gQ + (size_t)b * 1024;
    const float* __restrict__ Gb = gG + (size_t)b * (201 * 32);
    const float* __restrict__ QGb = USE_QG ? gQG + (size_t)b * (201 * 32) : nullptr;

    // ---------------- one-time staging ----------------
    #pragma unroll
    for (int m = 0; m < 4; ++m)
        reinterpret_cast<float4*>(sA)[lane + 64 * m] =
            reinterpret_cast<const float4*>(Ab)[lane + 64 * m];
    if constexpr (!USE_QG) {
        #pragma unroll
        for (int m = 0; m < 4; ++m)
            reinterpret_cast<float4*>(sQ)[lane + 64 * m] =
                reinterpret_cast<const float4*>(Qb)[lane + 64 * m];
    }
    // A^T tile for the v' row-major b128 reads
    #pragma unroll
    for (int t = 0; t < 16; ++t) {
        const int mm = 2 * t + up;
        sAt[col * 36 + mm] = Ab[mm * 32 + col];
    }
    {
        float4 b4 = reinterpret_cast<const float4*>(Bb)[lane];
        const int fb = lane * 4;
        sBp[((fb + 0) >> 3) * 9 + ((fb + 0) & 7)] = b4.x;
        sBp[((fb + 1) >> 3) * 9 + ((fb + 1) & 7)] = b4.y;
        sBp[((fb + 2) >> 3) * 9 + ((fb + 2) & 7)] = b4.z;
        sBp[((fb + 3) >> 3) * 9 + ((fb + 3) & 7)] = b4.w;
    }
    const float rreg = gR[(size_t)b * 64 + lane];   // R[ig][kg]

    // AtF: A-frag of A^T AND B-frag of A (both read A[k][col]).
    Frag2 AtF[2];
    #pragma unroll
    for (int h = 0; h < 2; ++h) {
        float f[8];
        #pragma unroll
        for (int e = 0; e < 8; ++e) f[e] = Ab[(16 * h + 8 * up + e) * 32 + col];
        AtF[h] = split2_8(f);
    }
    // B^T zero-padded to 32x32 as A-frag
    Frag2 BtF[2];
    #pragma unroll
    for (int h = 0; h < 2; ++h) {
        float f[8];
        #pragma unroll
        for (int e = 0; e < 8; ++e)
            f[e] = (col < 8) ? Bb[(16 * h + 8 * up + e) * 8 + col] : 0.f;
        BtF[h] = split2_8(f);
    }
    // B as A-operand for B*Kg (32x8 in one K=16 tile: k=8up+e, up=1 half zero)
    Frag2 BFa;
    {
        float f[8];
        #pragma unroll
        for (int e = 0; e < 8; ++e) f[e] = up ? 0.f : Bb[col * 8 + e];
        BFa = split2_8(f);
    }
    // A and Q in C/D layout (register-resident addends)
    f32x16 afr, qfr;
    #pragma unroll
    for (int r = 0; r < 16; ++r) {
        const int row = (r & 3) + 8 * (r >> 2) + 4 * up;
        afr[r] = Ab[row * 32 + col];
        qfr[r] = Qb[row * 32 + col];
    }

    // v0 = Q * goals[:, T, :]
    if constexpr (USE_QG) {
        if (lane < 32) svv[jj] = QGb[200 * 32 + jj];
    } else {
        const float* __restrict__ gl = Gb + 200 * 32;
        float t = 0.f;
        #pragma unroll
        for (int m = 0; m < 32; ++m) t += sQ[m * 32 + jj] * gl[m];
        if (lane < 32) svv[jj] = t;
    }

    // Persistent zero accumulator seed: every MFMA chain starts from these
    // regs instead of 16 v_mov zero-inits per chain per step (9 chains =
    // ~144 movs/step). Bit-identical: chains still start from 0.0.
    // (Isolated from R14's bundle — no setprio, no Atc.)
    f32x16 z16;
    #pragma unroll
    for (int r = 0; r < 16; ++r) z16[r] = 0.f;

    f32x16 vacc = qfr;   // V0 = Q, held in C/D layout across steps
    const float* __restrict__ qgp = USE_QG ? QGb + 199 * 32 : nullptr;

    for (int c = 0; c < NT; ++c) {
        const int step = NT - 1 - c;

        // t2 = (Q * goal_step)[jj] — one coalesced load (or fallback loop)
        float t2;
        if constexpr (USE_QG) {
            t2 = qgp[jj];
        } else {
            const float* __restrict__ grow = Gb + step * 32;
            t2 = 0.f;
            #pragma unroll
            for (int m = 0; m < 32; ++m) t2 += sQ[m * 32 + jj] * grow[m];
        }

        // ---- V (C/D regs) -> frag (B-frag layout), all-VALU permlane path
        Frag2 VF[2];
        cd_to_bfrag(vacc, VF);

        // ---- BtV = (B^T pad) V~ (1-acc small-first), then P = V~^T A
        f32x16 bacc, pC, pB;
        bacc = mm_lo(z16, BtF[0], VF[0]);
        bacc = mm_lo(bacc, BtF[1], VF[1]);
        bacc = mm_hh(bacc, BtF[0], VF[0]);
        bacc = mm_hh(bacc, BtF[1], VF[1]);
        pC = mm_lo(z16, VF[0], AtF[0]);
        pC = mm_lo(pC, VF[1], AtF[1]);
        pB = mm_hh(z16, VF[0], AtF[0]);
        pB = mm_hh(pB, VF[1], AtF[1]);

        // ---- btv[u] = sum_j B[j][u] * v[j] (VALU; overlaps MFMAs)
        {
            const int u = lane & 7, q8 = lane >> 3;
            const float4 v4 = *reinterpret_cast<const float4*>(&svv[4 * q8]);
            float p = 0.f;
            p += sBp[(4 * q8 + 0) * 9 + u] * v4.x;
            p += sBp[(4 * q8 + 1) * 9 + u] * v4.y;
            p += sBp[(4 * q8 + 2) * 9 + u] * v4.z;
            p += sBp[(4 * q8 + 3) * 9 + u] * v4.w;
            p += __shfl_xor(p, 8, 64);
            p += __shfl_xor(p, 16, 64);
            p += __shfl_xor(p, 32, 64);
            if (lane < 8) sbtv[u] = p;
        }

        // ---- BtV rows 0..7 -> LDS
        #pragma unroll
        for (int q = 0; q < 4; ++q)
            sBtV[(q + 4 * up) * 36 + col] = bacc[q];

        // ---- BtV as A-operand (transpose read of the LITERAL LDS BtV;
        //      rows >= 8 of the padded 32x32 are zero)
        Frag2 BtVaF[2];
        #pragma unroll
        for (int h = 0; h < 2; ++h) {
            float f[8];
            #pragma unroll
            for (int e = 0; e < 8; ++e)
                f[e] = (col < 8) ? sBtV[col * 36 + 16 * h + 8 * up + e] : 0.f;
            BtVaF[h] = split2_8(f);
        }

        // ---- M2 = BtV * A via MFMA (2-acc; B-op = AtF reused).
        f32x16 mC, mB;
        mC = mm_lo(z16, BtVaF[0], AtF[0]);
        mC = mm_lo(mC, BtVaF[1], AtF[1]);
        mB = mm_hh(z16, BtVaF[0], AtF[0]);
        mB = mm_hh(mB, BtVaF[1], AtF[1]);

        // ---- Vuu = R + BtV*B (slim fp32 loop; overlaps the M2 MFMAs)
        float cur, cur8;
        {
            float vu = rreg;
            #pragma unroll
            for (int jb = 0; jb < 8; ++jb) {
                const float4 bt4 = *reinterpret_cast<const float4*>(&sBtV[ig * 36 + 4 * jb]);
                vu += bt4.x * sBp[(4 * jb + 0) * 9 + kg];
                vu += bt4.y * sBp[(4 * jb + 1) * 9 + kg];
                vu += bt4.z * sBp[(4 * jb + 2) * 9 + kg];
                vu += bt4.w * sBp[(4 * jb + 3) * 9 + kg];
            }
            cur  = vu;
            cur8 = (ig == kg) ? 1.f : 0.f;
        }

        // ---- M2 merge -> LDS (rows q+4up; mC/mB die here, before GJ)
        #pragma unroll
        for (int q = 0; q < 4; ++q)
            sM2[(q + 4 * up) * 36 + col] = mC[q] + mB[q];

        // ---- Gauss-Jordan inverse of Vuu in registers via shfl.
        // Lane (ig,kg) holds [Vuu|I][ig][kg]. PD with diag>=1 -> no pivoting.
        #pragma unroll
        for (int p = 0; p < 8; ++p) {
            const float piv = __shfl(cur, p * 8 + p, 64);
            const float rp  = 1.0f / piv;
            const float pc  = __shfl(cur,  p * 8 + kg, 64);
            const float pc8 = __shfl(cur8, p * 8 + kg, 64);
            const float mrp = __shfl(cur,  ig * 8 + p, 64);
            const float fgj = mrp * rp;
            const bool  isp = (ig == p);
            cur  = isp ? pc  * rp : cur  - fgj * pc;
            cur8 = isp ? pc8 * rp : cur8 - fgj * pc8;
        }

        // ---- merge P, build P frag (B-frag layout; as A-op it is P^T = A^T V~)
        f32x16 pM;
        #pragma unroll
        for (int r = 0; r < 16; ++r) pM[r] = pC[r] + pB[r];
        Frag2 PF[2];
        cd_to_bfrag(pM, PF);

        // ---- P3: Kg = Vuu_inv * M2 ; kf = Vuu_inv * btv ; write outputs
        float* const sKg = sBtV;   // BtV dead after Vuu + BtVaF build
        {
            float ka0 = 0, ka1 = 0, ka2 = 0, ka3 = 0, kfv = 0;
            #pragma unroll
            for (int u2 = 0; u2 < 8; ++u2) {
                const float  w  = __shfl(cur8, ig * 8 + u2, 64);   // inv[ig][u2]
                const float4 m4 = *reinterpret_cast<const float4*>(&sM2[u2 * 36 + k0]);
                const float  bt = sbtv[u2];
                ka0 += w * m4.x; ka1 += w * m4.y; ka2 += w * m4.z; ka3 += w * m4.w;
                kfv += w * bt;
            }
            *reinterpret_cast<float4*>(&sKg[ig * 36 + k0]) = make_float4(ka0, ka1, ka2, ka3);
            const size_t ob = (size_t)step * NBATCH + b;
            *reinterpret_cast<float4*>(&outK[ob * 256 + ig * 32 + k0]) =
                make_float4(ka0, ka1, ka2, ka3);
            if (kg == 0) outk[ob * 8 + ig] = kfv;
        }

        // ---- Kg as B-operand (one K=16 tile: rows 8up+e; up=1 half zero)
        Frag2 KgF;
        {
            float fk[8];
            #pragma unroll
            for (int e = 0; e < 8; ++e)
                fk[e] = up ? 0.f : sKg[e * 36 + col];
            KgF = split2_8(fk);
        }

        // ---- BKg = B * Kg (emulated, 2-acc); ABK = A - BKg in fp32 (C/D regs)
        f32x16 bkC, bkB;
        bkC = mm_lo(z16, BFa, KgF);
        bkB = mm_hh(z16, BFa, KgF);
        f32x16 abk;
        #pragma unroll
        for (int r = 0; r < 16; ++r) abk[r] = afr[r] - (bkC[r] + bkB[r]);

        // ---- KF: ABK as B-frag (from registers; no LDS roundtrip)
        Frag2 KF[2];
        cd_to_bfrag(abk, KF);

        // ---- V' = P^T * ABK + Q (PF as A-op; 2-acc; Q added last in fp32)
        f32x16 vC, vB;
        vC = mm_lo(z16, PF[0], KF[0]);
        vC = mm_lo(vC, PF[1], KF[1]);
        vB = mm_hh(z16, PF[0], KF[0]);
        vB = mm_hh(vB, PF[1], KF[1]);

        // ---- v' = A^T v - Kg^T btv + QG (VALU; overlaps V' MFMAs)
        {
            float t1 = 0.f;
            #pragma unroll
            for (int kb = 0; kb < 8; ++kb) {
                const float4 a4 = *reinterpret_cast<const float4*>(&sAt[jj * 36 + 4 * kb]);
                const float4 v4 = *reinterpret_cast<const float4*>(&svv[4 * kb]);
                t1 += a4.x * v4.x; t1 += a4.y * v4.y;
                t1 += a4.z * v4.z; t1 += a4.w * v4.w;
            }
            float tk = 0.f;
            #pragma unroll
            for (int u = 0; u < 8; ++u) tk += sKg[u * 36 + jj] * sbtv[u];
            if (lane < 32) svv[jj] = (t1 - tk) + t2;
        }

        // ---- final merge: small terms first, Q last in fp32
        #pragma unroll
        for (int r = 0; r < 16; ++r) vacc[r] = (vC[r] + vB[r]) + qfr[r];

        if constexpr (USE_QG) qgp -= 32;
    }
}

}  // namespace

extern "C" void kernel_launch(void* const* d_in, const int* in_sizes, int n_in,
                              void* d_out, int out_size, void* d_ws, size_t ws_size,
                              hipStream_t stream) {
    const float* A = (const float*)d_in[0];
    const float* B = (const float*)d_in[1];
    const float* Q = (const float*)d_in[2];
    const float* R = (const float*)d_in[3];
    const float* G = (const float*)d_in[4];
    float* outK = (float*)d_out;
    float* outk = outK + (size_t)NT * NBATCH * 8 * 32;

    const size_t need = (size_t)NBATCH * 201 * 32 * sizeof(float);
    if (ws_size >= need) {
        float* QG = (float*)d_ws;
        qg_kernel<<<dim3(NBATCH), dim3(64), 0, stream>>>(Q, G, QG);
        lqr_kernel<true><<<dim3(NBATCH), dim3(64), 0, stream>>>(
            A, B, Q, R, G, QG, outK, outk);
    } else {
        lqr_kernel<false><<<dim3(NBATCH), dim3(64), 0, stream>>>(
            A, B, Q, R, G, nullptr, outK, outk);
    }
}

// Round 16
// 749.278 us; speedup vs baseline: 1.0959x; 1.0543x over previous
//
#include <hip/hip_runtime.h>

namespace {

constexpr int NBATCH = 2048;
constexpr int NT     = 200;

typedef _Float16 f16x8 __attribute__((ext_vector_type(8)));
typedef float    f32x16 __attribute__((ext_vector_type(16)));
typedef int      i32x2  __attribute__((ext_vector_type(2)));

struct Frag2 { f16x8 h, l; };

// Exact 2-way split of fp32 into f16 hi/lo (11-bit mantissa each, RTNE).
// r = v - h is exact in fp32 (Sterbenz); h + l represents v to ~2^-23 rel.
__device__ inline Frag2 split2_8(const float f[8]) {
  Frag2 r;
  #pragma unroll
  for (int e = 0; e < 8; ++e) {
    const float v = f[e];
    const _Float16 hH = (_Float16)v;         // RTNE
    const float r1 = v - (float)hH;          // exact
    r.h[e] = hH;
    r.l[e] = (_Float16)r1;                   // RTNE; drops ~2^-23 rel
  }
  return r;
}

// Cross-term group (lh, hl ~ 2^-11|D|) — accumulate separately from hh so
// rounding happens at ulp(2^-11|D|). Merge in fp32 VALU afterwards.
__device__ inline f32x16 mm_lo(f32x16 acc, const Frag2& a, const Frag2& b) {
  acc = __builtin_amdgcn_mfma_f32_32x32x16_f16(a.l, b.h, acc, 0, 0, 0);
  acc = __builtin_amdgcn_mfma_f32_32x32x16_f16(a.h, b.l, acc, 0, 0, 0);
  return acc;
}
__device__ inline f32x16 mm_hh(f32x16 acc, const Frag2& a, const Frag2& b) {
  return __builtin_amdgcn_mfma_f32_32x32x16_f16(a.h, b.h, acc, 0, 0, 0);
}

// v_permlane32_swap_b32: out0 = {a.lanes0-31, b.lanes0-31},
//                        out1 = {a.lanes32-63, b.lanes32-63}.
// Semantics hardware-verified in round 9 (bit-identical pass).
__device__ inline void half_swap(float a, float b, float& oa, float& ob) {
  i32x2 r = __builtin_amdgcn_permlane32_swap(
      __float_as_int(a), __float_as_int(b), false, false);
  oa = __int_as_float(r[0]);
  ob = __int_as_float(r[1]);
}

// C/D-layout regs -> B-operand Frag2 pair, all-VALU via permlane32_swap.
__device__ inline void cd_to_bfrag(const f32x16 cd, Frag2 out[2]) {
  #pragma unroll
  for (int h = 0; h < 2; ++h) {
    float f[8];
    const int base = 8 * h;
    #pragma unroll
    for (int e = 0; e < 4; ++e)
      half_swap(cd[base + e], cd[base + 4 + e], f[e], f[4 + e]);
    out[h] = split2_8(f);
  }
}

// Fast reciprocal: v_rcp_f32 (+~1e-5 rel) + 1 Newton step -> ~1-2 ulp.
// Replaces the IEEE div sequence (~10 dependent VALU + VCC) on the GJ
// critical path. Kg error through the inverse is relative; by optimality
// of the LQR gain it enters V' only at O(eps^2) — numerically safe.
__device__ inline float fast_rcp(float x) {
  float y = __builtin_amdgcn_rcpf(x);
  const float e = fmaf(-x, y, 1.0f);
  return fmaf(y, e, y);
}

// Precompute QG[b][t][j] = (Q_b * goal_t)[j] for t = 0..200.
// Same ascending-m FMA chain as the in-loop version -> bit-identical.
__global__ __launch_bounds__(64) void qg_kernel(
    const float* __restrict__ gQ, const float* __restrict__ gG,
    float* __restrict__ QG)
{
    __shared__ float sQ[1024];
    const int lane = threadIdx.x;
    const int b    = blockIdx.x;
    const float* __restrict__ Qb = gQ + (size_t)b * 1024;
    const float* __restrict__ Gb = gG + (size_t)b * (201 * 32);
    float* __restrict__ QGb = QG + (size_t)b * (201 * 32);
    #pragma unroll
    for (int m = 0; m < 4; ++m)
        reinterpret_cast<float4*>(sQ)[lane + 64 * m] =
            reinterpret_cast<const float4*>(Qb)[lane + 64 * m];
    const int jj = lane & 31, th = lane >> 5;
    for (int t = th; t < 201; t += 2) {
        const float* __restrict__ g = Gb + t * 32;
        float acc = 0.f;
        #pragma unroll
        for (int m = 0; m < 32; ++m) acc += sQ[m * 32 + jj] * g[m];
        QGb[t * 32 + jj] = acc;
    }
}

// One wave = one batch element, 200-step backward Riccati recursion.
// R4/R7-proven CONSISTENT algebra (every product consumes the same literal V~):
//   P   = V~^T A  (MFMA, VF-as-A-op) ; BtV = B^T V~ (MFMA) -> LDS
//   M2  = BtV * A (MFMA on the LITERAL LDS BtV; B-op = AtF reused)
//   Vuu = R + BtV*B (MFMA: BtVaF x BtF — A-frag of B^T == B-frag of B)
//   Kg  = Vuu^-1 M2 (shfl GJ, fast_rcp) ; ABK = A - B*Kg (fp32 cancel FIRST)
//   V'  = P^T * ABK + Q (MFMA, PF-as-A-op = literal P^T = A^T V~)
//   v'  = A^T v - Kg^T (B^T v) + QG[step]
// MFMA 32x32x16 layouts (verified rounds 2-4; f16 same mapping as bf16):
//   A-frag: lane holds A'[l&31][16h + 8*(l>>5) + e]
//   B-frag: lane holds B'[16h + 8*(l>>5) + e][l&31]
//   C/D   : lane holds C[(r&3) + 8*(r>>2) + 4*(l>>5)][l&31]
template <bool USE_QG>
__global__ __launch_bounds__(64, 2) void lqr_kernel(
    const float* __restrict__ gA,   // [B,32,32]
    const float* __restrict__ gB,   // [B,32,8]
    const float* __restrict__ gQ,   // [B,32,32]
    const float* __restrict__ gR,   // [B,8,8]
    const float* __restrict__ gG,   // [B,201,32]
    const float* __restrict__ gQG,  // [B,201,32] precomputed Q*goal (or null)
    float* __restrict__ outK,       // [T,B,8,32]
    float* __restrict__ outk)       // [T,B,8]
{
    __shared__ __attribute__((aligned(16))) float smem[4104];
    float* const sA   = smem;          // [32][32] row-major
    float* const sQ   = smem + 1024;   // [32][32] (fallback Q*goal only)
    float* const sAt  = smem + 2048;   // [32][36] A^T, pad 36 (v' b128 rows)
    float* const sBp  = smem + 3200;   // [32][9]  B padded (btv phase)
    float* const sBtV = smem + 3488;   // [8][36]  B^T V ; aliased as Kg later
    float* const sM2  = smem + 3776;   // [8][36]  BtV*A
    float* const svv  = smem + 4064;   // [32] running v
    float* const sbtv = smem + 4096;   // [8]  B^T v

    const int lane = threadIdx.x;
    const int b    = blockIdx.x;
    const int ig   = lane >> 3;        // 0..7
    const int kg   = lane & 7;         // 0..7
    const int k0   = kg << 2;
    const int jj   = lane & 31;
    const int col  = lane & 31;        // MFMA col within tile
    const int up   = lane >> 5;        // 0/1: lane-half

    const float* __restrict__ Ab = gA + (size_t)b * 1024;
    const float* __restrict__ Bb = gB + (size_t)b * 256;
    const float* __restrict__ Qb = gQ + (size_t)b * 1024;
    const float* __restrict__ Gb = gG + (size_t)b * (201 * 32);
    const float* __restrict__ QGb = USE_QG ? gQG + (size_t)b * (201 * 32) : nullptr;

    // ---------------- one-time staging ----------------
    #pragma unroll
    for (int m = 0; m < 4; ++m)
        reinterpret_cast<float4*>(sA)[lane + 64 * m] =
            reinterpret_cast<const float4*>(Ab)[lane + 64 * m];
    if constexpr (!USE_QG) {
        #pragma unroll
        for (int m = 0; m < 4; ++m)
            reinterpret_cast<float4*>(sQ)[lane + 64 * m] =
                reinterpret_cast<const float4*>(Qb)[lane + 64 * m];
    }
    // A^T tile for the v' row-major b128 reads
    #pragma unroll
    for (int t = 0; t < 16; ++t) {
        const int mm = 2 * t + up;
        sAt[col * 36 + mm] = Ab[mm * 32 + col];
    }
    {
        float4 b4 = reinterpret_cast<const float4*>(Bb)[lane];
        const int fb = lane * 4;
        sBp[((fb + 0) >> 3) * 9 + ((fb + 0) & 7)] = b4.x;
        sBp[((fb + 1) >> 3) * 9 + ((fb + 1) & 7)] = b4.y;
        sBp[((fb + 2) >> 3) * 9 + ((fb + 2) & 7)] = b4.z;
        sBp[((fb + 3) >> 3) * 9 + ((fb + 3) & 7)] = b4.w;
    }
    const float rreg = gR[(size_t)b * 64 + lane];   // R[ig][kg]

    // AtF: A-frag of A^T AND B-frag of A (both read A[k][col]).
    Frag2 AtF[2];
    #pragma unroll
    for (int h = 0; h < 2; ++h) {
        float f[8];
        #pragma unroll
        for (int e = 0; e < 8; ++e) f[e] = Ab[(16 * h + 8 * up + e) * 32 + col];
        AtF[h] = split2_8(f);
    }
    // B^T zero-padded to 32x32 as A-frag; ALSO the B-frag of B_pad (duality).
    Frag2 BtF[2];
    #pragma unroll
    for (int h = 0; h < 2; ++h) {
        float f[8];
        #pragma unroll
        for (int e = 0; e < 8; ++e)
            f[e] = (col < 8) ? Bb[(16 * h + 8 * up + e) * 8 + col] : 0.f;
        BtF[h] = split2_8(f);
    }
    // B as A-operand for B*Kg (32x8 in one K=16 tile: k=8up+e, up=1 half zero)
    Frag2 BFa;
    {
        float f[8];
        #pragma unroll
        for (int e = 0; e < 8; ++e) f[e] = up ? 0.f : Bb[col * 8 + e];
        BFa = split2_8(f);
    }
    // A and Q in C/D layout (register-resident addends)
    f32x16 afr, qfr;
    #pragma unroll
    for (int r = 0; r < 16; ++r) {
        const int row = (r & 3) + 8 * (r >> 2) + 4 * up;
        afr[r] = Ab[row * 32 + col];
        qfr[r] = Qb[row * 32 + col];
    }

    // v0 = Q * goals[:, T, :]
    if constexpr (USE_QG) {
        if (lane < 32) svv[jj] = QGb[200 * 32 + jj];
    } else {
        const float* __restrict__ gl = Gb + 200 * 32;
        float t = 0.f;
        #pragma unroll
        for (int m = 0; m < 32; ++m) t += sQ[m * 32 + jj] * gl[m];
        if (lane < 32) svv[jj] = t;
    }

    // Persistent zero accumulator seed (R15-proven neutral-or-better).
    f32x16 z16;
    #pragma unroll
    for (int r = 0; r < 16; ++r) z16[r] = 0.f;

    f32x16 vacc = qfr;   // V0 = Q, held in C/D layout across steps
    const float* __restrict__ qgp = USE_QG ? QGb + 199 * 32 : nullptr;

    for (int c = 0; c < NT; ++c) {
        const int step = NT - 1 - c;

        // t2 = (Q * goal_step)[jj] — one coalesced load (or fallback loop)
        float t2;
        if constexpr (USE_QG) {
            t2 = qgp[jj];
        } else {
            const float* __restrict__ grow = Gb + step * 32;
            t2 = 0.f;
            #pragma unroll
            for (int m = 0; m < 32; ++m) t2 += sQ[m * 32 + jj] * grow[m];
        }

        // ---- V (C/D regs) -> frag (B-frag layout), all-VALU permlane path
        Frag2 VF[2];
        cd_to_bfrag(vacc, VF);

        // ---- BtV = (B^T pad) V~ (1-acc small-first), then P = V~^T A
        f32x16 bacc, pC, pB;
        bacc = mm_lo(z16, BtF[0], VF[0]);
        bacc = mm_lo(bacc, BtF[1], VF[1]);
        bacc = mm_hh(bacc, BtF[0], VF[0]);
        bacc = mm_hh(bacc, BtF[1], VF[1]);
        pC = mm_lo(z16, VF[0], AtF[0]);
        pC = mm_lo(pC, VF[1], AtF[1]);
        pB = mm_hh(z16, VF[0], AtF[0]);
        pB = mm_hh(pB, VF[1], AtF[1]);

        // ---- btv[u] = sum_j B[j][u] * v[j] (VALU; overlaps MFMAs)
        {
            const int u = lane & 7, q8 = lane >> 3;
            const float4 v4 = *reinterpret_cast<const float4*>(&svv[4 * q8]);
            float p = 0.f;
            p += sBp[(4 * q8 + 0) * 9 + u] * v4.x;
            p += sBp[(4 * q8 + 1) * 9 + u] * v4.y;
            p += sBp[(4 * q8 + 2) * 9 + u] * v4.z;
            p += sBp[(4 * q8 + 3) * 9 + u] * v4.w;
            p += __shfl_xor(p, 8, 64);
            p += __shfl_xor(p, 16, 64);
            p += __shfl_xor(p, 32, 64);
            if (lane < 8) sbtv[u] = p;
        }

        // ---- BtV rows 0..7 -> LDS
        #pragma unroll
        for (int q = 0; q < 4; ++q)
            sBtV[(q + 4 * up) * 36 + col] = bacc[q];

        // ---- BtV as A-operand (transpose read of the LITERAL LDS BtV;
        //      rows >= 8 of the padded 32x32 are zero)
        Frag2 BtVaF[2];
        #pragma unroll
        for (int h = 0; h < 2; ++h) {
            float f[8];
            #pragma unroll
            for (int e = 0; e < 8; ++e)
                f[e] = (col < 8) ? sBtV[col * 36 + 16 * h + 8 * up + e] : 0.f;
            BtVaF[h] = split2_8(f);
        }

        // ---- M2 = BtV * A via MFMA (2-acc; B-op = AtF reused).
        f32x16 mC, mB;
        mC = mm_lo(z16, BtVaF[0], AtF[0]);
        mC = mm_lo(mC, BtVaF[1], AtF[1]);
        mB = mm_hh(z16, BtVaF[0], AtF[0]);
        mB = mm_hh(mB, BtVaF[1], AtF[1]);

        // ---- Vuu = R + BtV*B via MFMA: A-op = BtVaF (reused), B-op = BtF
        //      (A-frag of B^T == B-frag of B_pad, same duality as AtF).
        //      Output 8x8 in C/D rows/cols 0-7; redistribute to GJ layout.
        f32x16 vuuA;
        vuuA = mm_lo(z16, BtVaF[0], BtF[0]);
        vuuA = mm_lo(vuuA, BtVaF[1], BtF[1]);
        vuuA = mm_hh(vuuA, BtVaF[0], BtF[0]);
        vuuA = mm_hh(vuuA, BtVaF[1], BtF[1]);

        // Redistribute: Vuu[i][k] lives at C/D lane 32*(i>>2)+k, reg i&3.
        // GJ lane (ig,kg) pulls reg (ig&3) from lane 32*(ig>>2)+kg.
        float cur, cur8;
        {
            const int srcl = 32 * (ig >> 2) + kg;
            const float b0 = __shfl(vuuA[0], srcl, 64);
            const float b1 = __shfl(vuuA[1], srcl, 64);
            const float b2 = __shfl(vuuA[2], srcl, 64);
            const float b3 = __shfl(vuuA[3], srcl, 64);
            const float s01 = (ig & 1) ? b1 : b0;
            const float s23 = (ig & 1) ? b3 : b2;
            cur  = rreg + ((ig & 2) ? s23 : s01);
            cur8 = (ig == kg) ? 1.f : 0.f;
        }

        // ---- Gauss-Jordan inverse of Vuu in registers via shfl.
        // Lane (ig,kg) holds [Vuu|I][ig][kg]. PD with diag>=1 -> no pivoting.
        #pragma unroll
        for (int p = 0; p < 8; ++p) {
            const float piv = __shfl(cur, p * 8 + p, 64);
            const float rp  = fast_rcp(piv);
            const float pc  = __shfl(cur,  p * 8 + kg, 64);
            const float pc8 = __shfl(cur8, p * 8 + kg, 64);
            const float mrp = __shfl(cur,  ig * 8 + p, 64);
            const float fgj = mrp * rp;
            const bool  isp = (ig == p);
            cur  = isp ? pc  * rp : cur  - fgj * pc;
            cur8 = isp ? pc8 * rp : cur8 - fgj * pc8;
        }

        // ---- M2 merge -> LDS (after GJ: mC/mB stay out of the GJ window)
        #pragma unroll
        for (int q = 0; q < 4; ++q)
            sM2[(q + 4 * up) * 36 + col] = mC[q] + mB[q];

        // ---- merge P, build P frag (B-frag layout; as A-op it is P^T = A^T V~)
        f32x16 pM;
        #pragma unroll
        for (int r = 0; r < 16; ++r) pM[r] = pC[r] + pB[r];
        Frag2 PF[2];
        cd_to_bfrag(pM, PF);

        // ---- P3: Kg = Vuu_inv * M2 ; kf = Vuu_inv * btv ; write outputs
        float* const sKg = sBtV;   // BtV dead after BtVaF build
        {
            float ka0 = 0, ka1 = 0, ka2 = 0, ka3 = 0, kfv = 0;
            #pragma unroll
            for (int u2 = 0; u2 < 8; ++u2) {
                const float  w  = __shfl(cur8, ig * 8 + u2, 64);   // inv[ig][u2]
                const float4 m4 = *reinterpret_cast<const float4*>(&sM2[u2 * 36 + k0]);
                const float  bt = sbtv[u2];
                ka0 += w * m4.x; ka1 += w * m4.y; ka2 += w * m4.z; ka3 += w * m4.w;
                kfv += w * bt;
            }
            *reinterpret_cast<float4*>(&sKg[ig * 36 + k0]) = make_float4(ka0, ka1, ka2, ka3);
            const size_t ob = (size_t)step * NBATCH + b;
            *reinterpret_cast<float4*>(&outK[ob * 256 + ig * 32 + k0]) =
                make_float4(ka0, ka1, ka2, ka3);
            if (kg == 0) outk[ob * 8 + ig] = kfv;
        }

        // ---- Kg as B-operand (one K=16 tile: rows 8up+e; up=1 half zero)
        Frag2 KgF;
        {
            float fk[8];
            #pragma unroll
            for (int e = 0; e < 8; ++e)
                fk[e] = up ? 0.f : sKg[e * 36 + col];
            KgF = split2_8(fk);
        }

        // ---- BKg = B * Kg (emulated, 2-acc); ABK = A - BKg in fp32 (C/D regs)
        f32x16 bkC, bkB;
        bkC = mm_lo(z16, BFa, KgF);
        bkB = mm_hh(z16, BFa, KgF);
        f32x16 abk;
        #pragma unroll
        for (int r = 0; r < 16; ++r) abk[r] = afr[r] - (bkC[r] + bkB[r]);

        // ---- KF: ABK as B-frag (from registers; no LDS roundtrip)
        Frag2 KF[2];
        cd_to_bfrag(abk, KF);

        // ---- V' = P^T * ABK + Q (PF as A-op; 2-acc; Q added last in fp32)
        f32x16 vC, vB;
        vC = mm_lo(z16, PF[0], KF[0]);
        vC = mm_lo(vC, PF[1], KF[1]);
        vB = mm_hh(z16, PF[0], KF[0]);
        vB = mm_hh(vB, PF[1], KF[1]);

        // ---- v' = A^T v - Kg^T btv + QG (VALU; overlaps V' MFMAs)
        {
            float t1 = 0.f;
            #pragma unroll
            for (int kb = 0; kb < 8; ++kb) {
                const float4 a4 = *reinterpret_cast<const float4*>(&sAt[jj * 36 + 4 * kb]);
                const float4 v4 = *reinterpret_cast<const float4*>(&svv[4 * kb]);
                t1 += a4.x * v4.x; t1 += a4.y * v4.y;
                t1 += a4.z * v4.z; t1 += a4.w * v4.w;
            }
            float tk = 0.f;
            #pragma unroll
            for (int u = 0; u < 8; ++u) tk += sKg[u * 36 + jj] * sbtv[u];
            if (lane < 32) svv[jj] = (t1 - tk) + t2;
        }

        // ---- final merge: small terms first, Q last in fp32
        #pragma unroll
        for (int r = 0; r < 16; ++r) vacc[r] = (vC[r] + vB[r]) + qfr[r];

        if constexpr (USE_QG) qgp -= 32;
    }
}

}  // namespace

extern "C" void kernel_launch(void* const* d_in, const int* in_sizes, int n_in,
                              void* d_out, int out_size, void* d_ws, size_t ws_size,
                              hipStream_t stream) {
    const float* A = (const float*)d_in[0];
    const float* B = (const float*)d_in[1];
    const float* Q = (const float*)d_in[2];
    const float* R = (const float*)d_in[3];
    const float* G = (const float*)d_in[4];
    float* outK = (float*)d_out;
    float* outk = outK + (size_t)NT * NBATCH * 8 * 32;

    const size_t need = (size_t)NBATCH * 201 * 32 * sizeof(float);
    if (ws_size >= need) {
        float* QG = (float*)d_ws;
        qg_kernel<<<dim3(NBATCH), dim3(64), 0, stream>>>(Q, G, QG);
        lqr_kernel<true><<<dim3(NBATCH), dim3(64), 0, stream>>>(
            A, B, Q, R, G, QG, outK, outk);
    } else {
        lqr_kernel<false><<<dim3(NBATCH), dim3(64), 0, stream>>>(
            A, B, Q, R, G, nullptr, outK, outk);
    }
}

// Round 17
// 725.652 us; speedup vs baseline: 1.1316x; 1.0326x over previous
//
#include <hip/hip_runtime.h>

namespace {

constexpr int NBATCH = 2048;
constexpr int NT     = 200;

typedef _Float16 f16x8 __attribute__((ext_vector_type(8)));
typedef float    f32x16 __attribute__((ext_vector_type(16)));
typedef int      i32x2  __attribute__((ext_vector_type(2)));

struct Frag2 { f16x8 h, l; };

// Exact 2-way split of fp32 into f16 hi/lo (11-bit mantissa each, RTNE).
// r = v - h is exact in fp32 (Sterbenz); h + l represents v to ~2^-23 rel.
__device__ inline Frag2 split2_8(const float f[8]) {
  Frag2 r;
  #pragma unroll
  for (int e = 0; e < 8; ++e) {
    const float v = f[e];
    const _Float16 hH = (_Float16)v;         // RTNE
    const float r1 = v - (float)hH;          // exact
    r.h[e] = hH;
    r.l[e] = (_Float16)r1;                   // RTNE; drops ~2^-23 rel
  }
  return r;
}

// Cross-term group (lh, hl ~ 2^-11|D|) — accumulate separately from hh so
// rounding happens at ulp(2^-11|D|). Merge in fp32 VALU afterwards.
__device__ inline f32x16 mm_lo(f32x16 acc, const Frag2& a, const Frag2& b) {
  acc = __builtin_amdgcn_mfma_f32_32x32x16_f16(a.l, b.h, acc, 0, 0, 0);
  acc = __builtin_amdgcn_mfma_f32_32x32x16_f16(a.h, b.l, acc, 0, 0, 0);
  return acc;
}
__device__ inline f32x16 mm_hh(f32x16 acc, const Frag2& a, const Frag2& b) {
  return __builtin_amdgcn_mfma_f32_32x32x16_f16(a.h, b.h, acc, 0, 0, 0);
}

// v_permlane32_swap_b32: out0 = {a.lanes0-31, b.lanes0-31},
//                        out1 = {a.lanes32-63, b.lanes32-63}.
// Semantics hardware-verified in round 9 (bit-identical pass).
__device__ inline void half_swap(float a, float b, float& oa, float& ob) {
  i32x2 r = __builtin_amdgcn_permlane32_swap(
      __float_as_int(a), __float_as_int(b), false, false);
  oa = __int_as_float(r[0]);
  ob = __int_as_float(r[1]);
}

// C/D-layout regs -> B-operand Frag2 pair, all-VALU via permlane32_swap.
__device__ inline void cd_to_bfrag(const f32x16 cd, Frag2 out[2]) {
  #pragma unroll
  for (int h = 0; h < 2; ++h) {
    float f[8];
    const int base = 8 * h;
    #pragma unroll
    for (int e = 0; e < 4; ++e)
      half_swap(cd[base + e], cd[base + 4 + e], f[e], f[4 + e]);
    out[h] = split2_8(f);
  }
}

// Fast reciprocal: v_rcp_f32 + 1 Newton step -> ~1-2 ulp (R16-proven).
__device__ inline float fast_rcp(float x) {
  float y = __builtin_amdgcn_rcpf(x);
  const float e = fmaf(-x, y, 1.0f);
  return fmaf(y, e, y);
}

// Precompute QG[b][t][j] = (Q_b * goal_t)[j] for t = 0..200.
// Same ascending-m FMA chain as the in-loop version -> bit-identical.
__global__ __launch_bounds__(64) void qg_kernel(
    const float* __restrict__ gQ, const float* __restrict__ gG,
    float* __restrict__ QG)
{
    __shared__ float sQ[1024];
    const int lane = threadIdx.x;
    const int b    = blockIdx.x;
    const float* __restrict__ Qb = gQ + (size_t)b * 1024;
    const float* __restrict__ Gb = gG + (size_t)b * (201 * 32);
    float* __restrict__ QGb = QG + (size_t)b * (201 * 32);
    #pragma unroll
    for (int m = 0; m < 4; ++m)
        reinterpret_cast<float4*>(sQ)[lane + 64 * m] =
            reinterpret_cast<const float4*>(Qb)[lane + 64 * m];
    const int jj = lane & 31, th = lane >> 5;
    for (int t = th; t < 201; t += 2) {
        const float* __restrict__ g = Gb + t * 32;
        float acc = 0.f;
        #pragma unroll
        for (int m = 0; m < 32; ++m) acc += sQ[m * 32 + jj] * g[m];
        QGb[t * 32 + jj] = acc;
    }
}

// One wave = one batch element, 200-step backward Riccati recursion.
// R4/R7-proven CONSISTENT algebra (every product consumes the same literal V~):
//   P   = V~^T A  (MFMA, VF-as-A-op) ; BtV = B^T V~ (MFMA) -> LDS
//   M2  = BtV * A (MFMA on the LITERAL LDS BtV; B-op = AtF reused)
//   Vuu = R + BtV*B (MFMA: BtVaF x BtF — A-frag of B^T == B-frag of B)
//   Kg  = Vuu^-1 M2 (shfl GJ, fast_rcp) ; ABK = A - B*Kg (fp32 cancel FIRST)
//   V'  = P^T * ABK + Q (MFMA, PF-as-A-op = literal P^T = A^T V~)
//   v'  = A^T v - Kg^T (B^T v) + QG[step]
// MFMA 32x32x16 layouts (verified rounds 2-4; f16 same mapping as bf16):
//   A-frag: lane holds A'[l&31][16h + 8*(l>>5) + e]
//   B-frag: lane holds B'[16h + 8*(l>>5) + e][l&31]
//   C/D   : lane holds C[(r&3) + 8*(r>>2) + 4*(l>>5)][l&31]
template <bool USE_QG>
__global__ __launch_bounds__(64, 2) void lqr_kernel(
    const float* __restrict__ gA,   // [B,32,32]
    const float* __restrict__ gB,   // [B,32,8]
    const float* __restrict__ gQ,   // [B,32,32]
    const float* __restrict__ gR,   // [B,8,8]
    const float* __restrict__ gG,   // [B,201,32]
    const float* __restrict__ gQG,  // [B,201,32] precomputed Q*goal (or null)
    float* __restrict__ outK,       // [T,B,8,32]
    float* __restrict__ outk)       // [T,B,8]
{
    __shared__ __attribute__((aligned(16))) float smem[4488];
    float* const sA   = smem;          // [32][32] row-major
    float* const sQ   = smem + 1024;   // [32][32] (fallback Q*goal only)
    float* const sAt  = smem + 2048;   // [32][36] A^T, pad 36 (v' b128 rows)
    float* const sBp  = smem + 3200;   // [32][9]  B padded (btv phase)
    float* const sBtV = smem + 3488;   // [8][36]  B^T V
    float* const sM2  = smem + 3776;   // [8][36]  BtV*A
    float* const svv  = smem + 4064;   // [32] running v
    float* const sbtv = smem + 4096;   // [8]  B^T v
    float* const sKgT = smem + 4104;   // [32][12] Kg TRANSPOSED: [c*12+r]=Kg[r][c]

    const int lane = threadIdx.x;
    const int b    = blockIdx.x;
    const int ig   = lane >> 3;        // 0..7
    const int kg   = lane & 7;         // 0..7
    const int k0   = kg << 2;
    const int jj   = lane & 31;
    const int col  = lane & 31;        // MFMA col within tile
    const int up   = lane >> 5;        // 0/1: lane-half

    const float* __restrict__ Ab = gA + (size_t)b * 1024;
    const float* __restrict__ Bb = gB + (size_t)b * 256;
    const float* __restrict__ Qb = gQ + (size_t)b * 1024;
    const float* __restrict__ Gb = gG + (size_t)b * (201 * 32);
    const float* __restrict__ QGb = USE_QG ? gQG + (size_t)b * (201 * 32) : nullptr;

    // ---------------- one-time staging ----------------
    #pragma unroll
    for (int m = 0; m < 4; ++m)
        reinterpret_cast<float4*>(sA)[lane + 64 * m] =
            reinterpret_cast<const float4*>(Ab)[lane + 64 * m];
    if constexpr (!USE_QG) {
        #pragma unroll
        for (int m = 0; m < 4; ++m)
            reinterpret_cast<float4*>(sQ)[lane + 64 * m] =
                reinterpret_cast<const float4*>(Qb)[lane + 64 * m];
    }
    // A^T tile for the v' row-major b128 reads
    #pragma unroll
    for (int t = 0; t < 16; ++t) {
        const int mm = 2 * t + up;
        sAt[col * 36 + mm] = Ab[mm * 32 + col];
    }
    {
        float4 b4 = reinterpret_cast<const float4*>(Bb)[lane];
        const int fb = lane * 4;
        sBp[((fb + 0) >> 3) * 9 + ((fb + 0) & 7)] = b4.x;
        sBp[((fb + 1) >> 3) * 9 + ((fb + 1) & 7)] = b4.y;
        sBp[((fb + 2) >> 3) * 9 + ((fb + 2) & 7)] = b4.z;
        sBp[((fb + 3) >> 3) * 9 + ((fb + 3) & 7)] = b4.w;
    }
    const float rreg = gR[(size_t)b * 64 + lane];   // R[ig][kg]

    // AtF: A-frag of A^T AND B-frag of A (both read A[k][col]).
    Frag2 AtF[2];
    #pragma unroll
    for (int h = 0; h < 2; ++h) {
        float f[8];
        #pragma unroll
        for (int e = 0; e < 8; ++e) f[e] = Ab[(16 * h + 8 * up + e) * 32 + col];
        AtF[h] = split2_8(f);
    }
    // B^T zero-padded to 32x32 as A-frag; ALSO the B-frag of B_pad (duality).
    Frag2 BtF[2];
    #pragma unroll
    for (int h = 0; h < 2; ++h) {
        float f[8];
        #pragma unroll
        for (int e = 0; e < 8; ++e)
            f[e] = (col < 8) ? Bb[(16 * h + 8 * up + e) * 8 + col] : 0.f;
        BtF[h] = split2_8(f);
    }
    // B as A-operand for B*Kg (32x8 in one K=16 tile: k=8up+e, up=1 half zero)
    Frag2 BFa;
    {
        float f[8];
        #pragma unroll
        for (int e = 0; e < 8; ++e) f[e] = up ? 0.f : Bb[col * 8 + e];
        BFa = split2_8(f);
    }
    // A and Q in C/D layout (register-resident addends)
    f32x16 afr, qfr;
    #pragma unroll
    for (int r = 0; r < 16; ++r) {
        const int row = (r & 3) + 8 * (r >> 2) + 4 * up;
        afr[r] = Ab[row * 32 + col];
        qfr[r] = Qb[row * 32 + col];
    }

    // v0 = Q * goals[:, T, :]
    if constexpr (USE_QG) {
        if (lane < 32) svv[jj] = QGb[200 * 32 + jj];
    } else {
        const float* __restrict__ gl = Gb + 200 * 32;
        float t = 0.f;
        #pragma unroll
        for (int m = 0; m < 32; ++m) t += sQ[m * 32 + jj] * gl[m];
        if (lane < 32) svv[jj] = t;
    }

    // Persistent zero accumulator seed (R15-proven neutral-or-better).
    f32x16 z16;
    #pragma unroll
    for (int r = 0; r < 16; ++r) z16[r] = 0.f;

    f32x16 vacc = qfr;   // V0 = Q, held in C/D layout across steps
    const float* __restrict__ qgp = USE_QG ? QGb + 199 * 32 : nullptr;

    for (int c = 0; c < NT; ++c) {
        const int step = NT - 1 - c;

        // t2 = (Q * goal_step)[jj] — one coalesced load (or fallback loop)
        float t2;
        if constexpr (USE_QG) {
            t2 = qgp[jj];
        } else {
            const float* __restrict__ grow = Gb + step * 32;
            t2 = 0.f;
            #pragma unroll
            for (int m = 0; m < 32; ++m) t2 += sQ[m * 32 + jj] * grow[m];
        }

        // ---- V (C/D regs) -> frag (B-frag layout), all-VALU permlane path
        Frag2 VF[2];
        cd_to_bfrag(vacc, VF);

        // ---- BtV = (B^T pad) V~ (1-acc small-first), then P = V~^T A
        f32x16 bacc, pC, pB;
        bacc = mm_lo(z16, BtF[0], VF[0]);
        bacc = mm_lo(bacc, BtF[1], VF[1]);
        bacc = mm_hh(bacc, BtF[0], VF[0]);
        bacc = mm_hh(bacc, BtF[1], VF[1]);
        pC = mm_lo(z16, VF[0], AtF[0]);
        pC = mm_lo(pC, VF[1], AtF[1]);
        pB = mm_hh(z16, VF[0], AtF[0]);
        pB = mm_hh(pB, VF[1], AtF[1]);

        // ---- btv[u] = sum_j B[j][u] * v[j] (VALU; overlaps MFMAs)
        {
            const int u = lane & 7, q8 = lane >> 3;
            const float4 v4 = *reinterpret_cast<const float4*>(&svv[4 * q8]);
            float p = 0.f;
            p += sBp[(4 * q8 + 0) * 9 + u] * v4.x;
            p += sBp[(4 * q8 + 1) * 9 + u] * v4.y;
            p += sBp[(4 * q8 + 2) * 9 + u] * v4.z;
            p += sBp[(4 * q8 + 3) * 9 + u] * v4.w;
            p += __shfl_xor(p, 8, 64);
            p += __shfl_xor(p, 16, 64);
            p += __shfl_xor(p, 32, 64);
            if (lane < 8) sbtv[u] = p;
        }

        // ---- BtV rows 0..7 -> LDS
        #pragma unroll
        for (int q = 0; q < 4; ++q)
            sBtV[(q + 4 * up) * 36 + col] = bacc[q];

        // ---- BtV as A-operand (transpose read of the LITERAL LDS BtV;
        //      rows >= 8 of the padded 32x32 are zero). b128 reads: the 8
        //      addresses per half are consecutive and 16B-aligned.
        Frag2 BtVaF[2];
        #pragma unroll
        for (int h = 0; h < 2; ++h) {
            float f[8];
            if (col < 8) {
                const float* base = &sBtV[col * 36 + 16 * h + 8 * up];
                const float4 a = *reinterpret_cast<const float4*>(base);
                const float4 d = *reinterpret_cast<const float4*>(base + 4);
                f[0] = a.x; f[1] = a.y; f[2] = a.z; f[3] = a.w;
                f[4] = d.x; f[5] = d.y; f[6] = d.z; f[7] = d.w;
            } else {
                #pragma unroll
                for (int e = 0; e < 8; ++e) f[e] = 0.f;
            }
            BtVaF[h] = split2_8(f);
        }

        // ---- M2 = BtV * A via MFMA (2-acc; B-op = AtF reused).
        f32x16 mC, mB;
        mC = mm_lo(z16, BtVaF[0], AtF[0]);
        mC = mm_lo(mC, BtVaF[1], AtF[1]);
        mB = mm_hh(z16, BtVaF[0], AtF[0]);
        mB = mm_hh(mB, BtVaF[1], AtF[1]);

        // ---- Vuu = R + BtV*B via MFMA: A-op = BtVaF (reused), B-op = BtF.
        f32x16 vuuA;
        vuuA = mm_lo(z16, BtVaF[0], BtF[0]);
        vuuA = mm_lo(vuuA, BtVaF[1], BtF[1]);
        vuuA = mm_hh(vuuA, BtVaF[0], BtF[0]);
        vuuA = mm_hh(vuuA, BtVaF[1], BtF[1]);

        // Redistribute: Vuu[i][k] lives at C/D lane 32*(i>>2)+k, reg i&3.
        // GJ lane (ig,kg) pulls reg (ig&3) from lane 32*(ig>>2)+kg.
        float cur, cur8;
        {
            const int srcl = 32 * (ig >> 2) + kg;
            const float b0 = __shfl(vuuA[0], srcl, 64);
            const float b1 = __shfl(vuuA[1], srcl, 64);
            const float b2 = __shfl(vuuA[2], srcl, 64);
            const float b3 = __shfl(vuuA[3], srcl, 64);
            const float s01 = (ig & 1) ? b1 : b0;
            const float s23 = (ig & 1) ? b3 : b2;
            cur  = rreg + ((ig & 2) ? s23 : s01);
            cur8 = (ig == kg) ? 1.f : 0.f;
        }

        // ---- Gauss-Jordan inverse of Vuu in registers via shfl.
        // Lane (ig,kg) holds [Vuu|I][ig][kg]. PD with diag>=1 -> no pivoting.
        #pragma unroll
        for (int p = 0; p < 8; ++p) {
            const float piv = __shfl(cur, p * 8 + p, 64);
            const float rp  = fast_rcp(piv);
            const float pc  = __shfl(cur,  p * 8 + kg, 64);
            const float pc8 = __shfl(cur8, p * 8 + kg, 64);
            const float mrp = __shfl(cur,  ig * 8 + p, 64);
            const float fgj = mrp * rp;
            const bool  isp = (ig == p);
            cur  = isp ? pc  * rp : cur  - fgj * pc;
            cur8 = isp ? pc8 * rp : cur8 - fgj * pc8;
        }

        // ---- M2 merge -> LDS (after GJ: mC/mB stay out of the GJ window)
        #pragma unroll
        for (int q = 0; q < 4; ++q)
            sM2[(q + 4 * up) * 36 + col] = mC[q] + mB[q];

        // ---- merge P, build P frag (B-frag layout; as A-op it is P^T = A^T V~)
        f32x16 pM;
        #pragma unroll
        for (int r = 0; r < 16; ++r) pM[r] = pC[r] + pB[r];
        Frag2 PF[2];
        cd_to_bfrag(pM, PF);

        // ---- P3: Kg = Vuu_inv * M2 ; kf = Vuu_inv * btv ; write outputs.
        //      Kg stored TRANSPOSED (sKgT[c*12+r] = Kg[r][c]) so KgF and tk
        //      become b128 row reads instead of scalar column reads.
        {
            float ka0 = 0, ka1 = 0, ka2 = 0, ka3 = 0, kfv = 0;
            #pragma unroll
            for (int u2 = 0; u2 < 8; ++u2) {
                const float  w  = __shfl(cur8, ig * 8 + u2, 64);   // inv[ig][u2]
                const float4 m4 = *reinterpret_cast<const float4*>(&sM2[u2 * 36 + k0]);
                const float  bt = sbtv[u2];
                ka0 += w * m4.x; ka1 += w * m4.y; ka2 += w * m4.z; ka3 += w * m4.w;
                kfv += w * bt;
            }
            sKgT[(k0 + 0) * 12 + ig] = ka0;
            sKgT[(k0 + 1) * 12 + ig] = ka1;
            sKgT[(k0 + 2) * 12 + ig] = ka2;
            sKgT[(k0 + 3) * 12 + ig] = ka3;
            const size_t ob = (size_t)step * NBATCH + b;
            *reinterpret_cast<float4*>(&outK[ob * 256 + ig * 32 + k0]) =
                make_float4(ka0, ka1, ka2, ka3);
            if (kg == 0) outk[ob * 8 + ig] = kfv;
        }

        // ---- Kg as B-operand (one K=16 tile: rows 8up+e; up=1 half zero)
        Frag2 KgF;
        {
            float fk[8];
            if (up == 0) {
                const float4 a = *reinterpret_cast<const float4*>(&sKgT[col * 12]);
                const float4 d = *reinterpret_cast<const float4*>(&sKgT[col * 12 + 4]);
                fk[0] = a.x; fk[1] = a.y; fk[2] = a.z; fk[3] = a.w;
                fk[4] = d.x; fk[5] = d.y; fk[6] = d.z; fk[7] = d.w;
            } else {
                #pragma unroll
                for (int e = 0; e < 8; ++e) fk[e] = 0.f;
            }
            KgF = split2_8(fk);
        }

        // ---- BKg = B * Kg (emulated, 2-acc); ABK = A - BKg in fp32 (C/D regs)
        f32x16 bkC, bkB;
        bkC = mm_lo(z16, BFa, KgF);
        bkB = mm_hh(z16, BFa, KgF);
        f32x16 abk;
        #pragma unroll
        for (int r = 0; r < 16; ++r) abk[r] = afr[r] - (bkC[r] + bkB[r]);

        // ---- KF: ABK as B-frag (from registers; no LDS roundtrip)
        Frag2 KF[2];
        cd_to_bfrag(abk, KF);

        // ---- V' = P^T * ABK + Q (PF as A-op; 2-acc; Q added last in fp32)
        f32x16 vC, vB;
        vC = mm_lo(z16, PF[0], KF[0]);
        vC = mm_lo(vC, PF[1], KF[1]);
        vB = mm_hh(z16, PF[0], KF[0]);
        vB = mm_hh(vB, PF[1], KF[1]);

        // ---- v' = A^T v - Kg^T btv + QG (VALU; overlaps V' MFMAs)
        {
            float t1 = 0.f;
            #pragma unroll
            for (int kb = 0; kb < 8; ++kb) {
                const float4 a4 = *reinterpret_cast<const float4*>(&sAt[jj * 36 + 4 * kb]);
                const float4 v4 = *reinterpret_cast<const float4*>(&svv[4 * kb]);
                t1 += a4.x * v4.x; t1 += a4.y * v4.y;
                t1 += a4.z * v4.z; t1 += a4.w * v4.w;
            }
            // tk = sum_u Kg[u][jj]*btv[u] via transposed row reads (ascending u)
            const float4 kg0 = *reinterpret_cast<const float4*>(&sKgT[jj * 12]);
            const float4 kg1 = *reinterpret_cast<const float4*>(&sKgT[jj * 12 + 4]);
            const float4 bt0 = *reinterpret_cast<const float4*>(&sbtv[0]);
            const float4 bt1 = *reinterpret_cast<const float4*>(&sbtv[4]);
            float tk = 0.f;
            tk += kg0.x * bt0.x; tk += kg0.y * bt0.y;
            tk += kg0.z * bt0.z; tk += kg0.w * bt0.w;
            tk += kg1.x * bt1.x; tk += kg1.y * bt1.y;
            tk += kg1.z * bt1.z; tk += kg1.w * bt1.w;
            if (lane < 32) svv[jj] = (t1 - tk) + t2;
        }

        // ---- final merge: small terms first, Q last in fp32
        #pragma unroll
        for (int r = 0; r < 16; ++r) vacc[r] = (vC[r] + vB[r]) + qfr[r];

        if constexpr (USE_QG) qgp -= 32;
    }
}

}  // namespace

extern "C" void kernel_launch(void* const* d_in, const int* in_sizes, int n_in,
                              void* d_out, int out_size, void* d_ws, size_t ws_size,
                              hipStream_t stream) {
    const float* A = (const float*)d_in[0];
    const float* B = (const float*)d_in[1];
    const float* Q = (const float*)d_in[2];
    const float* R = (const float*)d_in[3];
    const float* G = (const float*)d_in[4];
    float* outK = (float*)d_out;
    float* outk = outK + (size_t)NT * NBATCH * 8 * 32;

    const size_t need = (size_t)NBATCH * 201 * 32 * sizeof(float);
    if (ws_size >= need) {
        float* QG = (float*)d_ws;
        qg_kernel<<<dim3(NBATCH), dim3(64), 0, stream>>>(Q, G, QG);
        lqr_kernel<true><<<dim3(NBATCH), dim3(64), 0, stream>>>(
            A, B, Q, R, G, QG, outK, outk);
    } else {
        lqr_kernel<false><<<dim3(NBATCH), dim3(64), 0, stream>>>(
            A, B, Q, R, G, nullptr, outK, outk);
    }
}